// Round 4
// baseline (1094.318 us; speedup 1.0000x reference)
//
#include <hip/hip_runtime.h>

// ---------------------------------------------------------------------------
// ResidualGCN: 3x (GCNConv -> BN -> ReLU (+res)) -> Linear head
// N=100000 nodes, E=1.6M edges, dims 128/128/64, fp32 throughout.
//
// Strategy:
//   - edge_index dtype probed ON DEVICE (JAX w/o x64 gives int32 despite the
//     reference saying int64; harness spec says integer -> const int*).
//   - Build CSR by target column once per launch (hist + 2-level scan + fill),
//     reused by all 3 conv layers. Self-loop handled analytically.
//   - Conv = wave-per-node gather: coalesced 512B row loads, no float atomics.
//   - GEMM: fp32 vector, 64-row LDS A-tile, 8x4 register tile.
//   - BN: single-pass sum/sumsq atomics -> finalize -> fused apply+relu+res.
// ---------------------------------------------------------------------------

// One wave: decide whether edge_index is int64 (flag=1) or int32 (flag=0).
// If int64 (little-endian, values in [0, 2^31)), every odd int32 word of the
// first 64 elements is 0. For genuine int32 data (uniform [0,N)), the chance
// all 64 sampled words are 0 is ~0.
__global__ void detect_i64(const int* __restrict__ ei32, int* __restrict__ flag) {
  int lane = threadIdx.x & 63;
  int v = ei32[2 * lane + 1];
  unsigned long long b = __ballot(v == 0);
  if (lane == 0) *flag = (b == ~0ull) ? 1 : 0;
}

__global__ __launch_bounds__(256) void init_k(float* __restrict__ deg,
                                              int* __restrict__ cnt,
                                              float* __restrict__ stats, int n) {
  int i = blockIdx.x * 256 + threadIdx.x;
  if (i < n) { deg[i] = 1.0f; cnt[i] = 0; }   // deg starts at 1.0 (self loop w=1)
  if (i < 768) stats[i] = 0.0f;               // 3 layers x (sum[128], sumsq[128])
}

// histogram by target column
__global__ __launch_bounds__(256) void edge_hist(const int* __restrict__ ei32,
                                                 const float* __restrict__ w,
                                                 float* __restrict__ deg,
                                                 int* __restrict__ cnt,
                                                 const int* __restrict__ flag, int e) {
  int i = blockIdx.x * 256 + threadIdx.x;
  if (i >= e) return;
  int is64 = *flag;                      // uniform; L2-broadcast
  int c = is64 ? ei32[2 * (e + i)] : ei32[e + i];
  atomicAdd(&deg[c], w[i]);
  atomicAdd(&cnt[c], 1);
}

__global__ __launch_bounds__(256) void scan_blocksum(const int* __restrict__ cnt,
                                                     int* __restrict__ bsum, int n) {
  __shared__ int s[256];
  int i = blockIdx.x * 256 + threadIdx.x;
  s[threadIdx.x] = (i < n) ? cnt[i] : 0;
  __syncthreads();
  for (int off = 128; off > 0; off >>= 1) {
    if (threadIdx.x < off) s[threadIdx.x] += s[threadIdx.x + off];
    __syncthreads();
  }
  if (threadIdx.x == 0) bsum[blockIdx.x] = s[0];
}

// single-block exclusive scan of bsum[nb] (in place), chunked by 256 with carry
__global__ __launch_bounds__(256) void scan_small(int* __restrict__ bsum, int nb) {
  __shared__ int s[256];
  __shared__ int carry_s;
  if (threadIdx.x == 0) carry_s = 0;
  __syncthreads();
  for (int base = 0; base < nb; base += 256) {
    int idx = base + threadIdx.x;
    int v = (idx < nb) ? bsum[idx] : 0;
    s[threadIdx.x] = v;
    __syncthreads();
    for (int off = 1; off < 256; off <<= 1) {
      int t = (threadIdx.x >= (unsigned)off) ? s[threadIdx.x - off] : 0;
      __syncthreads();
      s[threadIdx.x] += t;
      __syncthreads();
    }
    int carry = carry_s;
    if (idx < nb) bsum[idx] = carry + s[threadIdx.x] - v;  // exclusive
    __syncthreads();
    if (threadIdx.x == 255) carry_s = carry + s[255];
    __syncthreads();
  }
}

__global__ __launch_bounds__(256) void scan_final(const int* __restrict__ cnt,
                                                  const int* __restrict__ boff,
                                                  int* __restrict__ rowptr,
                                                  int* __restrict__ fill,
                                                  const float* __restrict__ deg,
                                                  float* __restrict__ dinv,
                                                  int n, int e_total) {
  __shared__ int s[256];
  int i = blockIdx.x * 256 + threadIdx.x;
  int v = (i < n) ? cnt[i] : 0;
  s[threadIdx.x] = v;
  __syncthreads();
  for (int off = 1; off < 256; off <<= 1) {
    int t = (threadIdx.x >= (unsigned)off) ? s[threadIdx.x - off] : 0;
    __syncthreads();
    s[threadIdx.x] += t;
    __syncthreads();
  }
  if (i < n) {
    int start = boff[blockIdx.x] + s[threadIdx.x] - v;
    rowptr[i] = start;
    fill[i] = start;
    float d = deg[i];
    dinv[i] = (d > 0.f) ? rsqrtf(d) : 0.f;
  }
  if (i == 0) rowptr[n] = e_total;
}

__global__ __launch_bounds__(256) void edge_fill(const int* __restrict__ ei32,
                                                 const float* __restrict__ w,
                                                 const float* __restrict__ dinv,
                                                 int* __restrict__ fill,
                                                 int2* __restrict__ csr,
                                                 const int* __restrict__ flag, int e) {
  int i = blockIdx.x * 256 + threadIdx.x;
  if (i >= e) return;
  int is64 = *flag;
  int r, c;
  if (is64) { r = ei32[2 * i]; c = ei32[2 * (e + i)]; }
  else      { r = ei32[i];     c = ei32[e + i]; }
  float nrm = dinv[r] * w[i] * dinv[c];
  int pos = atomicAdd(&fill[c], 1);
  csr[pos] = make_int2(r, __float_as_int(nrm));
}

// out[N,OC] = A[N,128] @ W[128,OC] (+ bias). OC = 32*CPT (128 or 64).
template <int CPT>
__global__ __launch_bounds__(256) void gemm_k128(const float* __restrict__ A,
                                                 const float* __restrict__ W,
                                                 const float* __restrict__ bias,
                                                 float* __restrict__ out, int n) {
  constexpr int OC = 32 * CPT;
  __shared__ float As[64][128];
  const int tid = threadIdx.x;
  const int r0 = blockIdx.x * 64;
  // stage A tile (64x128 fp32 = 32 KB), coalesced float4
  #pragma unroll
  for (int i = 0; i < 8; ++i) {
    int idx = tid + i * 256;          // 0..2047 float4 slots
    int row = idx >> 5;
    int c4 = (idx & 31) << 2;
    float4 v = make_float4(0.f, 0.f, 0.f, 0.f);
    int gr = r0 + row;
    if (gr < n) v = *reinterpret_cast<const float4*>(&A[(size_t)gr * 128 + c4]);
    *reinterpret_cast<float4*>(&As[row][c4]) = v;
  }
  __syncthreads();

  const int lc = (tid & 31) * CPT;    // col start
  const int lr = (tid >> 5) * 8;      // row start within tile
  float acc[8][CPT];
  #pragma unroll
  for (int i = 0; i < 8; ++i)
    #pragma unroll
    for (int j = 0; j < CPT; ++j) acc[i][j] = 0.f;

  #pragma unroll 2
  for (int k4 = 0; k4 < 128; k4 += 4) {
    float a[8][4];
    #pragma unroll
    for (int i = 0; i < 8; ++i) {
      float4 t = *reinterpret_cast<const float4*>(&As[lr + i][k4]);
      a[i][0] = t.x; a[i][1] = t.y; a[i][2] = t.z; a[i][3] = t.w;
    }
    #pragma unroll
    for (int kk = 0; kk < 4; ++kk) {
      float wv[CPT];
      const float* wrow = &W[(size_t)(k4 + kk) * OC + lc];
      if constexpr (CPT == 4) {
        float4 t = *reinterpret_cast<const float4*>(wrow);
        wv[0] = t.x; wv[1] = t.y; wv[2] = t.z; wv[3] = t.w;
      } else {
        float2 t = *reinterpret_cast<const float2*>(wrow);
        wv[0] = t.x; wv[1] = t.y;
      }
      #pragma unroll
      for (int i = 0; i < 8; ++i)
        #pragma unroll
        for (int j = 0; j < CPT; ++j)
          acc[i][j] = fmaf(a[i][kk], wv[j], acc[i][j]);
    }
  }

  float bv[CPT];
  #pragma unroll
  for (int j = 0; j < CPT; ++j) bv[j] = bias ? bias[lc + j] : 0.f;
  #pragma unroll
  for (int i = 0; i < 8; ++i) {
    int gr = r0 + lr + i;
    if (gr < n) {
      if constexpr (CPT == 4) {
        float4 o = make_float4(acc[i][0] + bv[0], acc[i][1] + bv[1],
                               acc[i][2] + bv[2], acc[i][3] + bv[3]);
        *reinterpret_cast<float4*>(&out[(size_t)gr * OC + lc]) = o;
      } else {
        float2 o = make_float2(acc[i][0] + bv[0], acc[i][1] + bv[1]);
        *reinterpret_cast<float2*>(&out[(size_t)gr * OC + lc]) = o;
      }
    }
  }
}

// wave-per-node CSR gather: out[i] = sum_e norm_e * h[src_e] + dinv[i]^2 * h[i] + b
// 4-deep inner unroll: four independent 512B row loads in flight per wave.
__global__ __launch_bounds__(256) void gcn_gather(const float* __restrict__ h,
                                                  const int* __restrict__ rowptr,
                                                  const int2* __restrict__ csr,
                                                  const float* __restrict__ dinv,
                                                  const float* __restrict__ bias,
                                                  float* __restrict__ out, int n) {
  int wave = threadIdx.x >> 6;
  int lane = threadIdx.x & 63;
  int node = blockIdx.x * 4 + wave;
  if (node >= n) return;
  const float2* hp = reinterpret_cast<const float2*>(h);
  float di = dinv[node];
  float2 hv = hp[(size_t)node * 64 + lane];
  float s = di * di;
  float ax = s * hv.x, ay = s * hv.y;
  int e0 = rowptr[node], e1 = rowptr[node + 1];
  int e = e0;
  for (; e + 3 < e1; e += 4) {
    int2 pa = csr[e];
    int2 pb = csr[e + 1];
    int2 pc = csr[e + 2];
    int2 pd = csr[e + 3];
    float2 sa = hp[(size_t)pa.x * 64 + lane];
    float2 sb = hp[(size_t)pb.x * 64 + lane];
    float2 sc = hp[(size_t)pc.x * 64 + lane];
    float2 sd = hp[(size_t)pd.x * 64 + lane];
    float na = __int_as_float(pa.y), nb = __int_as_float(pb.y);
    float nc = __int_as_float(pc.y), nd = __int_as_float(pd.y);
    ax = fmaf(na, sa.x, ax); ay = fmaf(na, sa.y, ay);
    ax = fmaf(nb, sb.x, ax); ay = fmaf(nb, sb.y, ay);
    ax = fmaf(nc, sc.x, ax); ay = fmaf(nc, sc.y, ay);
    ax = fmaf(nd, sd.x, ax); ay = fmaf(nd, sd.y, ay);
  }
  for (; e < e1; ++e) {
    int2 p = csr[e];
    float2 sv = hp[(size_t)p.x * 64 + lane];
    float nm = __int_as_float(p.y);
    ax = fmaf(nm, sv.x, ax); ay = fmaf(nm, sv.y, ay);
  }
  int f = lane * 2;
  float bx = bias ? bias[f] : 0.f;
  float by = bias ? bias[f + 1] : 0.f;
  float2 o = make_float2(ax + bx, ay + by);
  reinterpret_cast<float2*>(out)[(size_t)node * 64 + lane] = o;
}

__global__ __launch_bounds__(256) void bn_stats(const float* __restrict__ h,
                                                float* __restrict__ stats, int n) {
  int f = threadIdx.x & 127;
  int half = threadIdx.x >> 7;
  float s = 0.f, q = 0.f;
  for (int r = blockIdx.x * 2 + half; r < n; r += gridDim.x * 2) {
    float v = h[(size_t)r * 128 + f];
    s += v;
    q = fmaf(v, v, q);
  }
  __shared__ float ls[256], lq[256];
  ls[threadIdx.x] = s; lq[threadIdx.x] = q;
  __syncthreads();
  if (half == 0) {
    s += ls[threadIdx.x + 128];
    q += lq[threadIdx.x + 128];
    atomicAdd(&stats[f], s);
    atomicAdd(&stats[128 + f], q);
  }
}

__global__ void bn_finalize(const float* __restrict__ stats,
                            const float* __restrict__ g,
                            const float* __restrict__ be,
                            float* __restrict__ scsh, float inv_n) {
  int f = threadIdx.x;  // 128 threads
  float mean = stats[f] * inv_n;
  float var = stats[128 + f] * inv_n - mean * mean;
  float sc = g[f] * rsqrtf(var + 1e-5f);
  scsh[f] = sc;
  scsh[128 + f] = be[f] - mean * sc;
}

template <bool RES>
__global__ __launch_bounds__(256) void bn_apply(const float* __restrict__ c,
                                                const float* __restrict__ res,
                                                const float* __restrict__ scsh,
                                                float* __restrict__ out, int n4) {
  int i = blockIdx.x * 256 + threadIdx.x;  // float4 index
  if (i >= n4) return;
  int f4 = (i & 31) * 4;
  float4 v = reinterpret_cast<const float4*>(c)[i];
  float4 sc = *reinterpret_cast<const float4*>(&scsh[f4]);
  float4 sh = *reinterpret_cast<const float4*>(&scsh[128 + f4]);
  float4 o;
  o.x = fmaf(v.x, sc.x, sh.x);
  o.y = fmaf(v.y, sc.y, sh.y);
  o.z = fmaf(v.z, sc.z, sh.z);
  o.w = fmaf(v.w, sc.w, sh.w);
  if (RES) {
    float4 r = reinterpret_cast<const float4*>(res)[i];
    o.x += r.x; o.y += r.y; o.z += r.z; o.w += r.w;
  }
  o.x = fmaxf(o.x, 0.f); o.y = fmaxf(o.y, 0.f);
  o.z = fmaxf(o.z, 0.f); o.w = fmaxf(o.w, 0.f);
  reinterpret_cast<float4*>(out)[i] = o;
}

extern "C" void kernel_launch(void* const* d_in, const int* in_sizes, int n_in,
                              void* d_out, int out_size, void* d_ws, size_t ws_size,
                              hipStream_t stream) {
  const float* x   = (const float*)d_in[0];
  const int*   ei  = (const int*)d_in[1];      // int32 on device (probed for int64)
  const float* ew  = (const float*)d_in[2];
  const float* W1  = (const float*)d_in[3];
  const float* b1  = (const float*)d_in[4];
  const float* g1  = (const float*)d_in[5];
  const float* be1 = (const float*)d_in[6];
  const float* W2  = (const float*)d_in[7];
  const float* b2  = (const float*)d_in[8];
  const float* g2  = (const float*)d_in[9];
  const float* be2 = (const float*)d_in[10];
  const float* W3  = (const float*)d_in[11];
  const float* b3  = (const float*)d_in[12];
  const float* g3  = (const float*)d_in[13];
  const float* be3 = (const float*)d_in[14];
  const float* Wh  = (const float*)d_in[15];
  const float* bh  = (const float*)d_in[16];

  const int N = in_sizes[0] / 128;
  const int E = in_sizes[2];

  char* base = (char*)d_ws;
  size_t off = 0;
  auto alloc = [&](size_t bytes) -> void* {
    off = (off + 511) & ~size_t(511);
    void* p = base + off;
    off += bytes;
    return p;
  };
  int*   flag   = (int*)alloc(4);
  float* deg    = (float*)alloc((size_t)N * 4);
  float* dinv   = (float*)alloc((size_t)N * 4);
  int*   cnt    = (int*)alloc((size_t)N * 4);
  int*   fillp  = (int*)alloc((size_t)N * 4);
  int*   rowptr = (int*)alloc((size_t)(N + 1) * 4);
  int*   bsum   = (int*)alloc(1024 * 4);
  float* stats  = (float*)alloc(768 * 4);
  float* scsh   = (float*)alloc(256 * 4);
  int2*  csr    = (int2*)alloc((size_t)E * 8);
  float* X0     = (float*)alloc((size_t)N * 128 * 4);
  float* X1     = (float*)alloc((size_t)N * 128 * 4);
  float* X2     = (float*)alloc((size_t)N * 128 * 4);
  (void)ws_size; (void)n_in; (void)out_size;

  const int nb = (N + 255) / 256;
  const int eb = (E + 255) / 256;
  const int gb = (N + 63) / 64;
  const int cb = (N + 3) / 4;
  const int ab = (N * 32 + 255) / 256;

  // ---- graph normalization + CSR build ----
  detect_i64<<<1, 64, 0, stream>>>(ei, flag);
  init_k<<<nb, 256, 0, stream>>>(deg, cnt, stats, N);
  edge_hist<<<eb, 256, 0, stream>>>(ei, ew, deg, cnt, flag, E);
  scan_blocksum<<<nb, 256, 0, stream>>>(cnt, bsum, N);
  scan_small<<<1, 256, 0, stream>>>(bsum, nb);
  scan_final<<<nb, 256, 0, stream>>>(cnt, bsum, rowptr, fillp, deg, dinv, N, E);
  edge_fill<<<eb, 256, 0, stream>>>(ei, ew, dinv, fillp, csr, flag, E);

  // ---- layer 1: x -> X0(gemm) -> X1(conv) -> X2(h1) ----
  gemm_k128<4><<<gb, 256, 0, stream>>>(x, W1, (const float*)nullptr, X0, N);
  gcn_gather<<<cb, 256, 0, stream>>>(X0, rowptr, csr, dinv, b1, X1, N);
  bn_stats<<<512, 256, 0, stream>>>(X1, stats + 0, N);
  bn_finalize<<<1, 128, 0, stream>>>(stats + 0, g1, be1, scsh, 1.0f / N);
  bn_apply<false><<<ab, 256, 0, stream>>>(X1, (const float*)nullptr, scsh, X2, N * 32);

  // ---- layer 2: X2 -> X0(gemm) -> X1(conv) -> X0(h2, res=X2) ----
  gemm_k128<4><<<gb, 256, 0, stream>>>(X2, W2, (const float*)nullptr, X0, N);
  gcn_gather<<<cb, 256, 0, stream>>>(X0, rowptr, csr, dinv, b2, X1, N);
  bn_stats<<<512, 256, 0, stream>>>(X1, stats + 256, N);
  bn_finalize<<<1, 128, 0, stream>>>(stats + 256, g2, be2, scsh, 1.0f / N);
  bn_apply<true><<<ab, 256, 0, stream>>>(X1, X2, scsh, X0, N * 32);

  // ---- layer 3: X0 -> X1(gemm) -> X2(conv) -> X1(h3, res=X0) ----
  gemm_k128<4><<<gb, 256, 0, stream>>>(X0, W3, (const float*)nullptr, X1, N);
  gcn_gather<<<cb, 256, 0, stream>>>(X1, rowptr, csr, dinv, b3, X2, N);
  bn_stats<<<512, 256, 0, stream>>>(X2, stats + 512, N);
  bn_finalize<<<1, 128, 0, stream>>>(stats + 512, g3, be3, scsh, 1.0f / N);
  bn_apply<true><<<ab, 256, 0, stream>>>(X2, X0, scsh, X1, N * 32);

  // ---- head: d_out = X1 @ Wh + bh ----
  gemm_k128<2><<<gb, 256, 0, stream>>>(X1, Wh, bh, (float*)d_out, N);
}

// Round 8
// 988.259 us; speedup vs baseline: 1.1073x; 1.1073x over previous
//
#include <hip/hip_runtime.h>

// ---------------------------------------------------------------------------
// ResidualGCN: 3x (GCNConv -> BN -> ReLU (+res)) -> Linear head
// N=100000 nodes, E=1.6M edges, dims 128/128/64, fp32 throughout.
//
// R4 counters: edge_hist was the #1 kernel (147us), bound by 32B-per-atomic
// memory-side transactions (WRITE_SIZE/atomics == 32B exactly). R5:
//   - cnt+deg packed into ONE u64 atomic (halves hist atomic transactions);
//     deg quantized at 2^-31 (error ~1e-9/edge, negligible).
//   - atomic return value = edge rank -> edge_fill needs NO atomics at all.
// ---------------------------------------------------------------------------

typedef unsigned long long u64;
#define DEG_MASK 0xFFFFFFFFFFFFULL
#define WSCALE 2147483648.0f  // 2^31

// One wave: decide whether edge_index is int64 (flag=1) or int32 (flag=0).
// int64 with values < 2^31 => every odd 32-bit word of the first 64 elements
// is 0; genuine int32 uniform [0,N) => probability ~0 that all 64 are 0.
__global__ void detect_i64(const int* __restrict__ ei32, int* __restrict__ flag) {
  int lane = threadIdx.x & 63;
  int v = ei32[2 * lane + 1];
  unsigned long long b = __ballot(v == 0);
  if (lane == 0) *flag = (b == ~0ull) ? 1 : 0;
}

__global__ __launch_bounds__(256) void init_k(u64* __restrict__ packed,
                                              float* __restrict__ stats, int n) {
  int i = blockIdx.x * 256 + threadIdx.x;
  if (i < n) packed[i] = 0ull;       // [cnt:16 | sum(w)*2^31:48]
  if (i < 768) stats[i] = 0.0f;      // 3 layers x (sum[128], sumsq[128])
}

// histogram by target column: ONE packed 64-bit atomic per edge.
// Returned old value's high bits = this edge's rank within its node.
__global__ __launch_bounds__(256) void edge_hist(const int* __restrict__ ei32,
                                                 const float* __restrict__ w,
                                                 u64* __restrict__ packed,
                                                 unsigned short* __restrict__ rank,
                                                 const int* __restrict__ flag, int e) {
  int i = blockIdx.x * 256 + threadIdx.x;
  if (i >= e) return;
  int is64 = *flag;                      // uniform; L2-broadcast
  int c = is64 ? ei32[2 * (e + i)] : ei32[e + i];
  u64 add = ((u64)1 << 48) | (u64)(unsigned)__float2uint_rn(w[i] * WSCALE);
  u64 old = atomicAdd(&packed[c], add);
  rank[i] = (unsigned short)(old >> 48);
}

__global__ __launch_bounds__(256) void scan_blocksum(const u64* __restrict__ packed,
                                                     int* __restrict__ bsum, int n) {
  __shared__ int s[256];
  int i = blockIdx.x * 256 + threadIdx.x;
  s[threadIdx.x] = (i < n) ? (int)(packed[i] >> 48) : 0;
  __syncthreads();
  for (int off = 128; off > 0; off >>= 1) {
    if (threadIdx.x < off) s[threadIdx.x] += s[threadIdx.x + off];
    __syncthreads();
  }
  if (threadIdx.x == 0) bsum[blockIdx.x] = s[0];
}

// single-block exclusive scan of bsum[nb] (in place), chunked by 256 with carry
__global__ __launch_bounds__(256) void scan_small(int* __restrict__ bsum, int nb) {
  __shared__ int s[256];
  __shared__ int carry_s;
  if (threadIdx.x == 0) carry_s = 0;
  __syncthreads();
  for (int base = 0; base < nb; base += 256) {
    int idx = base + threadIdx.x;
    int v = (idx < nb) ? bsum[idx] : 0;
    s[threadIdx.x] = v;
    __syncthreads();
    for (int off = 1; off < 256; off <<= 1) {
      int t = (threadIdx.x >= (unsigned)off) ? s[threadIdx.x - off] : 0;
      __syncthreads();
      s[threadIdx.x] += t;
      __syncthreads();
    }
    int carry = carry_s;
    if (idx < nb) bsum[idx] = carry + s[threadIdx.x] - v;  // exclusive
    __syncthreads();
    if (threadIdx.x == 255) carry_s = carry + s[255];
    __syncthreads();
  }
}

__global__ __launch_bounds__(256) void scan_final(const u64* __restrict__ packed,
                                                  const int* __restrict__ boff,
                                                  int* __restrict__ rowptr,
                                                  float* __restrict__ dinv,
                                                  int n, int e_total) {
  __shared__ int s[256];
  int i = blockIdx.x * 256 + threadIdx.x;
  u64 p = (i < n) ? packed[i] : 0ull;
  int v = (int)(p >> 48);
  s[threadIdx.x] = v;
  __syncthreads();
  for (int off = 1; off < 256; off <<= 1) {
    int t = (threadIdx.x >= (unsigned)off) ? s[threadIdx.x - off] : 0;
    __syncthreads();
    s[threadIdx.x] += t;
    __syncthreads();
  }
  if (i < n) {
    rowptr[i] = boff[blockIdx.x] + s[threadIdx.x] - v;
    float deg = 1.0f + (float)(p & DEG_MASK) * (1.0f / WSCALE);  // self-loop +1
    dinv[i] = rsqrtf(deg);   // deg >= 1 always
  }
  if (i == 0) rowptr[n] = e_total;
}

// NO atomics: each edge's slot = rowptr[col] + rank (from hist atomic order).
__global__ __launch_bounds__(256) void edge_fill(const int* __restrict__ ei32,
                                                 const float* __restrict__ w,
                                                 const float* __restrict__ dinv,
                                                 const int* __restrict__ rowptr,
                                                 const unsigned short* __restrict__ rank,
                                                 int2* __restrict__ csr,
                                                 const int* __restrict__ flag, int e) {
  int i = blockIdx.x * 256 + threadIdx.x;
  if (i >= e) return;
  int is64 = *flag;
  int r, c;
  if (is64) { r = ei32[2 * i]; c = ei32[2 * (e + i)]; }
  else      { r = ei32[i];     c = ei32[e + i]; }
  float nrm = dinv[r] * w[i] * dinv[c];
  int pos = rowptr[c] + (int)rank[i];
  csr[pos] = make_int2(r, __float_as_int(nrm));
}

// out[N,OC] = A[N,128] @ W[128,OC] (+ bias). OC = 32*CPT (128 or 64).
template <int CPT>
__global__ __launch_bounds__(256) void gemm_k128(const float* __restrict__ A,
                                                 const float* __restrict__ W,
                                                 const float* __restrict__ bias,
                                                 float* __restrict__ out, int n) {
  constexpr int OC = 32 * CPT;
  __shared__ float As[64][128];
  const int tid = threadIdx.x;
  const int r0 = blockIdx.x * 64;
  // stage A tile (64x128 fp32 = 32 KB), coalesced float4
  #pragma unroll
  for (int i = 0; i < 8; ++i) {
    int idx = tid + i * 256;          // 0..2047 float4 slots
    int row = idx >> 5;
    int c4 = (idx & 31) << 2;
    float4 v = make_float4(0.f, 0.f, 0.f, 0.f);
    int gr = r0 + row;
    if (gr < n) v = *reinterpret_cast<const float4*>(&A[(size_t)gr * 128 + c4]);
    *reinterpret_cast<float4*>(&As[row][c4]) = v;
  }
  __syncthreads();

  const int lc = (tid & 31) * CPT;    // col start
  const int lr = (tid >> 5) * 8;      // row start within tile
  float acc[8][CPT];
  #pragma unroll
  for (int i = 0; i < 8; ++i)
    #pragma unroll
    for (int j = 0; j < CPT; ++j) acc[i][j] = 0.f;

  #pragma unroll 2
  for (int k4 = 0; k4 < 128; k4 += 4) {
    float a[8][4];
    #pragma unroll
    for (int i = 0; i < 8; ++i) {
      float4 t = *reinterpret_cast<const float4*>(&As[lr + i][k4]);
      a[i][0] = t.x; a[i][1] = t.y; a[i][2] = t.z; a[i][3] = t.w;
    }
    #pragma unroll
    for (int kk = 0; kk < 4; ++kk) {
      float wv[CPT];
      const float* wrow = &W[(size_t)(k4 + kk) * OC + lc];
      if constexpr (CPT == 4) {
        float4 t = *reinterpret_cast<const float4*>(wrow);
        wv[0] = t.x; wv[1] = t.y; wv[2] = t.z; wv[3] = t.w;
      } else {
        float2 t = *reinterpret_cast<const float2*>(wrow);
        wv[0] = t.x; wv[1] = t.y;
      }
      #pragma unroll
      for (int i = 0; i < 8; ++i)
        #pragma unroll
        for (int j = 0; j < CPT; ++j)
          acc[i][j] = fmaf(a[i][kk], wv[j], acc[i][j]);
    }
  }

  float bv[CPT];
  #pragma unroll
  for (int j = 0; j < CPT; ++j) bv[j] = bias ? bias[lc + j] : 0.f;
  #pragma unroll
  for (int i = 0; i < 8; ++i) {
    int gr = r0 + lr + i;
    if (gr < n) {
      if constexpr (CPT == 4) {
        float4 o = make_float4(acc[i][0] + bv[0], acc[i][1] + bv[1],
                               acc[i][2] + bv[2], acc[i][3] + bv[3]);
        *reinterpret_cast<float4*>(&out[(size_t)gr * OC + lc]) = o;
      } else {
        float2 o = make_float2(acc[i][0] + bv[0], acc[i][1] + bv[1]);
        *reinterpret_cast<float2*>(&out[(size_t)gr * OC + lc]) = o;
      }
    }
  }
}

// wave-per-node CSR gather: out[i] = sum_e norm_e * h[src_e] + dinv[i]^2 * h[i] + b
// 4-deep inner unroll: four independent 512B row loads in flight per wave.
__global__ __launch_bounds__(256) void gcn_gather(const float* __restrict__ h,
                                                  const int* __restrict__ rowptr,
                                                  const int2* __restrict__ csr,
                                                  const float* __restrict__ dinv,
                                                  const float* __restrict__ bias,
                                                  float* __restrict__ out, int n) {
  int wave = threadIdx.x >> 6;
  int lane = threadIdx.x & 63;
  int node = blockIdx.x * 4 + wave;
  if (node >= n) return;
  const float2* hp = reinterpret_cast<const float2*>(h);
  float di = dinv[node];
  float2 hv = hp[(size_t)node * 64 + lane];
  float s = di * di;
  float ax = s * hv.x, ay = s * hv.y;
  int e0 = rowptr[node], e1 = rowptr[node + 1];
  int e = e0;
  for (; e + 3 < e1; e += 4) {
    int2 pa = csr[e];
    int2 pb = csr[e + 1];
    int2 pc = csr[e + 2];
    int2 pd = csr[e + 3];
    float2 sa = hp[(size_t)pa.x * 64 + lane];
    float2 sb = hp[(size_t)pb.x * 64 + lane];
    float2 sc = hp[(size_t)pc.x * 64 + lane];
    float2 sd = hp[(size_t)pd.x * 64 + lane];
    float na = __int_as_float(pa.y), nb = __int_as_float(pb.y);
    float nc = __int_as_float(pc.y), nd = __int_as_float(pd.y);
    ax = fmaf(na, sa.x, ax); ay = fmaf(na, sa.y, ay);
    ax = fmaf(nb, sb.x, ax); ay = fmaf(nb, sb.y, ay);
    ax = fmaf(nc, sc.x, ax); ay = fmaf(nc, sc.y, ay);
    ax = fmaf(nd, sd.x, ax); ay = fmaf(nd, sd.y, ay);
  }
  for (; e < e1; ++e) {
    int2 p = csr[e];
    float2 sv = hp[(size_t)p.x * 64 + lane];
    float nm = __int_as_float(p.y);
    ax = fmaf(nm, sv.x, ax); ay = fmaf(nm, sv.y, ay);
  }
  int f = lane * 2;
  float bx = bias ? bias[f] : 0.f;
  float by = bias ? bias[f + 1] : 0.f;
  float2 o = make_float2(ax + bx, ay + by);
  reinterpret_cast<float2*>(out)[(size_t)node * 64 + lane] = o;
}

__global__ __launch_bounds__(256) void bn_stats(const float* __restrict__ h,
                                                float* __restrict__ stats, int n) {
  int f = threadIdx.x & 127;
  int half = threadIdx.x >> 7;
  float s = 0.f, q = 0.f;
  for (int r = blockIdx.x * 2 + half; r < n; r += gridDim.x * 2) {
    float v = h[(size_t)r * 128 + f];
    s += v;
    q = fmaf(v, v, q);
  }
  __shared__ float ls[256], lq[256];
  ls[threadIdx.x] = s; lq[threadIdx.x] = q;
  __syncthreads();
  if (half == 0) {
    s += ls[threadIdx.x + 128];
    q += lq[threadIdx.x + 128];
    atomicAdd(&stats[f], s);
    atomicAdd(&stats[128 + f], q);
  }
}

__global__ void bn_finalize(const float* __restrict__ stats,
                            const float* __restrict__ g,
                            const float* __restrict__ be,
                            float* __restrict__ scsh, float inv_n) {
  int f = threadIdx.x;  // 128 threads
  float mean = stats[f] * inv_n;
  float var = stats[128 + f] * inv_n - mean * mean;
  float sc = g[f] * rsqrtf(var + 1e-5f);
  scsh[f] = sc;
  scsh[128 + f] = be[f] - mean * sc;
}

template <bool RES>
__global__ __launch_bounds__(256) void bn_apply(const float* __restrict__ c,
                                                const float* __restrict__ res,
                                                const float* __restrict__ scsh,
                                                float* __restrict__ out, int n4) {
  int i = blockIdx.x * 256 + threadIdx.x;  // float4 index
  if (i >= n4) return;
  int f4 = (i & 31) * 4;
  float4 v = reinterpret_cast<const float4*>(c)[i];
  float4 sc = *reinterpret_cast<const float4*>(&scsh[f4]);
  float4 sh = *reinterpret_cast<const float4*>(&scsh[128 + f4]);
  float4 o;
  o.x = fmaf(v.x, sc.x, sh.x);
  o.y = fmaf(v.y, sc.y, sh.y);
  o.z = fmaf(v.z, sc.z, sh.z);
  o.w = fmaf(v.w, sc.w, sh.w);
  if (RES) {
    float4 r = reinterpret_cast<const float4*>(res)[i];
    o.x += r.x; o.y += r.y; o.z += r.z; o.w += r.w;
  }
  o.x = fmaxf(o.x, 0.f); o.y = fmaxf(o.y, 0.f);
  o.z = fmaxf(o.z, 0.f); o.w = fmaxf(o.w, 0.f);
  reinterpret_cast<float4*>(out)[i] = o;
}

extern "C" void kernel_launch(void* const* d_in, const int* in_sizes, int n_in,
                              void* d_out, int out_size, void* d_ws, size_t ws_size,
                              hipStream_t stream) {
  const float* x   = (const float*)d_in[0];
  const int*   ei  = (const int*)d_in[1];      // int32 on device (probed for int64)
  const float* ew  = (const float*)d_in[2];
  const float* W1  = (const float*)d_in[3];
  const float* b1  = (const float*)d_in[4];
  const float* g1  = (const float*)d_in[5];
  const float* be1 = (const float*)d_in[6];
  const float* W2  = (const float*)d_in[7];
  const float* b2  = (const float*)d_in[8];
  const float* g2  = (const float*)d_in[9];
  const float* be2 = (const float*)d_in[10];
  const float* W3  = (const float*)d_in[11];
  const float* b3  = (const float*)d_in[12];
  const float* g3  = (const float*)d_in[13];
  const float* be3 = (const float*)d_in[14];
  const float* Wh  = (const float*)d_in[15];
  const float* bh  = (const float*)d_in[16];

  const int N = in_sizes[0] / 128;
  const int E = in_sizes[2];

  char* base = (char*)d_ws;
  size_t off = 0;
  auto alloc = [&](size_t bytes) -> void* {
    off = (off + 511) & ~size_t(511);
    void* p = base + off;
    off += bytes;
    return p;
  };
  int*            flag   = (int*)alloc(4);
  u64*            packed = (u64*)alloc((size_t)N * 8);
  float*          dinv   = (float*)alloc((size_t)N * 4);
  int*            rowptr = (int*)alloc((size_t)(N + 1) * 4);
  int*            bsum   = (int*)alloc(1024 * 4);
  float*          stats  = (float*)alloc(768 * 4);
  float*          scsh   = (float*)alloc(256 * 4);
  unsigned short* rank   = (unsigned short*)alloc((size_t)E * 2);
  int2*           csr    = (int2*)alloc((size_t)E * 8);
  float*          X0     = (float*)alloc((size_t)N * 128 * 4);
  float*          X1     = (float*)alloc((size_t)N * 128 * 4);
  float*          X2     = (float*)alloc((size_t)N * 128 * 4);
  (void)ws_size; (void)n_in; (void)out_size;

  const int nb = (N + 255) / 256;
  const int eb = (E + 255) / 256;
  const int gb = (N + 63) / 64;
  const int cb = (N + 3) / 4;
  const int ab = (N * 32 + 255) / 256;

  // ---- graph normalization + CSR build ----
  detect_i64<<<1, 64, 0, stream>>>(ei, flag);
  init_k<<<nb, 256, 0, stream>>>(packed, stats, N);
  edge_hist<<<eb, 256, 0, stream>>>(ei, ew, packed, rank, flag, E);
  scan_blocksum<<<nb, 256, 0, stream>>>(packed, bsum, N);
  scan_small<<<1, 256, 0, stream>>>(bsum, nb);
  scan_final<<<nb, 256, 0, stream>>>(packed, bsum, rowptr, dinv, N, E);
  edge_fill<<<eb, 256, 0, stream>>>(ei, ew, dinv, rowptr, rank, csr, flag, E);

  // ---- layer 1: x -> X0(gemm) -> X1(conv) -> X2(h1) ----
  gemm_k128<4><<<gb, 256, 0, stream>>>(x, W1, (const float*)nullptr, X0, N);
  gcn_gather<<<cb, 256, 0, stream>>>(X0, rowptr, csr, dinv, b1, X1, N);
  bn_stats<<<512, 256, 0, stream>>>(X1, stats + 0, N);
  bn_finalize<<<1, 128, 0, stream>>>(stats + 0, g1, be1, scsh, 1.0f / N);
  bn_apply<false><<<ab, 256, 0, stream>>>(X1, (const float*)nullptr, scsh, X2, N * 32);

  // ---- layer 2: X2 -> X0(gemm) -> X1(conv) -> X0(h2, res=X2) ----
  gemm_k128<4><<<gb, 256, 0, stream>>>(X2, W2, (const float*)nullptr, X0, N);
  gcn_gather<<<cb, 256, 0, stream>>>(X0, rowptr, csr, dinv, b2, X1, N);
  bn_stats<<<512, 256, 0, stream>>>(X1, stats + 256, N);
  bn_finalize<<<1, 128, 0, stream>>>(stats + 256, g2, be2, scsh, 1.0f / N);
  bn_apply<true><<<ab, 256, 0, stream>>>(X1, X2, scsh, X0, N * 32);

  // ---- layer 3: X0 -> X1(gemm) -> X2(conv) -> X1(h3, res=X0) ----
  gemm_k128<4><<<gb, 256, 0, stream>>>(X0, W3, (const float*)nullptr, X1, N);
  gcn_gather<<<cb, 256, 0, stream>>>(X1, rowptr, csr, dinv, b3, X2, N);
  bn_stats<<<512, 256, 0, stream>>>(X2, stats + 512, N);
  bn_finalize<<<1, 128, 0, stream>>>(stats + 512, g3, be3, scsh, 1.0f / N);
  bn_apply<true><<<ab, 256, 0, stream>>>(X2, X0, scsh, X1, N * 32);

  // ---- head: d_out = X1 @ Wh + bh ----
  gemm_k128<2><<<gb, 256, 0, stream>>>(X1, Wh, bh, (float*)d_out, N);
}